// Round 1
// baseline (346.431 us; speedup 1.0000x reference)
//
#include <hip/hip_runtime.h>
#include <hip/hip_bf16.h>

#define BTOT 65536
#define DDIM 512
#define CDIM 1000
#define CPAD 1024
#define KSEL 45875   // int(65536 * 0.7)

#define L2E 1.44269504088896340736f
#define LN2 0.69314718055994530942f
#define NEG_BIG -1.0e30f

typedef __attribute__((ext_vector_type(8))) short short8;
typedef __attribute__((ext_vector_type(4))) float f32x4;

__device__ __forceinline__ unsigned short f2bf(float f) {
  // round-to-nearest-even fp32 -> bf16
  unsigned u = __float_as_uint(f);
  u += 0x7FFFu + ((u >> 16) & 1u);
  return (unsigned short)(u >> 16);
}

// ---------------- prep: W [512][1000] f32 -> Wt [1024][512] bf16 (transposed, zero-padded) ----
__global__ void prep_wt(const float* __restrict__ W, unsigned short* __restrict__ Wt) {
  const int idx = blockIdx.x * 256 + threadIdx.x;   // 0 .. 1024*512-1, d fastest
  const int c = idx >> 9;
  const int d = idx & 511;
  unsigned short v = 0;
  if (c < CDIM) v = f2bf(W[d * CDIM + c]);
  Wt[idx] = v;   // coalesced bf16 writes
}

// bias pre-scaled by log2(e); padded classes get -1e30 (acts as the column mask)
__global__ void prep_bias(const float* __restrict__ b, float* __restrict__ bp) {
  const int i = blockIdx.x * 256 + threadIdx.x;     // < 1024
  bp[i] = (i < CDIM) ? b[i] * L2E : NEG_BIG;
}

// ---------------- fused GEMM + online logsumexp + target-logit extraction ----------------
// grid 512 x 256 threads (4 waves). Each wave owns 32 rows; A panel lives in registers.
__launch_bounds__(256, 2)
__global__ void ohem_losses(const float* __restrict__ feat,
                            const int* __restrict__ targets,
                            const unsigned short* __restrict__ Wt,
                            const float* __restrict__ bpad,
                            float* __restrict__ losses) {
  const int lane  = threadIdx.x & 63;
  const int wave  = (blockIdx.x << 2) + (threadIdx.x >> 6);
  const int rowB  = wave << 5;          // 32 rows per wave
  const int l15   = lane & 15;
  const int lgrp  = lane >> 4;          // 0..3

  // ---- load A fragments: a[rf][ks] holds rows rowB+rf*16+l15, k = ks*32 + lgrp*8 + j ----
  short8 a[2][16];
#pragma unroll
  for (int rf = 0; rf < 2; ++rf) {
    const float* src = feat + (size_t)(rowB + rf * 16 + l15) * DDIM + lgrp * 8;
#pragma unroll
    for (int ks = 0; ks < 16; ++ks) {
      const float4 f0 = *(const float4*)(src + ks * 32);
      const float4 f1 = *(const float4*)(src + ks * 32 + 4);
      short8 v;
      v[0] = (short)f2bf(f0.x); v[1] = (short)f2bf(f0.y);
      v[2] = (short)f2bf(f0.z); v[3] = (short)f2bf(f0.w);
      v[4] = (short)f2bf(f1.x); v[5] = (short)f2bf(f1.y);
      v[6] = (short)f2bf(f1.z); v[7] = (short)f2bf(f1.w);
      a[rf][ks] = v;
    }
  }

  // per-lane state: slot = rf*4 + r covers row rowB + rf*16 + lgrp*4 + r
  int   tcol[8];
  float m[8], s[8], tv[8];
#pragma unroll
  for (int rf = 0; rf < 2; ++rf)
#pragma unroll
    for (int r = 0; r < 4; ++r) {
      const int slot = rf * 4 + r;
      tcol[slot] = targets[rowB + rf * 16 + lgrp * 4 + r];
      m[slot] = NEG_BIG; s[slot] = 0.f; tv[slot] = NEG_BIG;
    }

  // ---- loop over 32 column-chunks of 32 classes ----
  for (int nc = 0; nc < 32; ++nc) {
    const int n0 = nc * 32;
    f32x4 acc[2][2];
#pragma unroll
    for (int rf = 0; rf < 2; ++rf)
#pragma unroll
      for (int cf = 0; cf < 2; ++cf) acc[rf][cf] = (f32x4){0.f, 0.f, 0.f, 0.f};

    const unsigned short* w0 = Wt + (size_t)(n0 + l15) * DDIM + lgrp * 8;
#pragma unroll
    for (int ks = 0; ks < 16; ++ks) {
      const short8 b0 = *(const short8*)(w0 + ks * 32);
      const short8 b1 = *(const short8*)(w0 + 16 * DDIM + ks * 32);
      acc[0][0] = __builtin_amdgcn_mfma_f32_16x16x32_bf16(a[0][ks], b0, acc[0][0], 0, 0, 0);
      acc[0][1] = __builtin_amdgcn_mfma_f32_16x16x32_bf16(a[0][ks], b1, acc[0][1], 0, 0, 0);
      acc[1][0] = __builtin_amdgcn_mfma_f32_16x16x32_bf16(a[1][ks], b0, acc[1][0], 0, 0, 0);
      acc[1][1] = __builtin_amdgcn_mfma_f32_16x16x32_bf16(a[1][ks], b1, acc[1][1], 0, 0, 0);
    }

    const int col0 = n0 + l15;
    const int col1 = col0 + 16;
    const float bb0 = bpad[col0];   // pre-scaled by log2e; -1e30 masks padded cols
    const float bb1 = bpad[col1];
#pragma unroll
    for (int rf = 0; rf < 2; ++rf)
#pragma unroll
      for (int r = 0; r < 4; ++r) {
        const int slot = rf * 4 + r;
        const float z0 = fmaf(acc[rf][0][r], L2E, bb0);
        const float z1 = fmaf(acc[rf][1][r], L2E, bb1);
        if (col0 == tcol[slot]) tv[slot] = z0;
        if (col1 == tcol[slot]) tv[slot] = z1;
        const float nm = fmaxf(m[slot], fmaxf(z0, z1));
        s[slot] = s[slot] * exp2f(m[slot] - nm) + exp2f(z0 - nm) + exp2f(z1 - nm);
        m[slot] = nm;
      }
  }

  // ---- merge (m,s) and target logit across the 16-lane group ----
#pragma unroll
  for (int st = 1; st <= 8; st <<= 1) {
#pragma unroll
    for (int slot = 0; slot < 8; ++slot) {
      const float mo = __shfl_xor(m[slot], st, 64);
      const float so = __shfl_xor(s[slot], st, 64);
      const float to = __shfl_xor(tv[slot], st, 64);
      const float nm = fmaxf(m[slot], mo);
      s[slot]  = s[slot] * exp2f(m[slot] - nm) + so * exp2f(mo - nm);
      m[slot]  = nm;
      tv[slot] = fmaxf(tv[slot], to);
    }
  }

  if (l15 == 0) {
#pragma unroll
    for (int rf = 0; rf < 2; ++rf)
#pragma unroll
      for (int r = 0; r < 4; ++r) {
        const int slot = rf * 4 + r;
        losses[rowB + rf * 16 + lgrp * 4 + r] =
            LN2 * (m[slot] + log2f(s[slot]) - tv[slot]);
      }
  }
}

// ---------------- exact k-th largest via 4x 8-bit radix passes (single block) ----------------
__global__ void radix_pass(const unsigned* __restrict__ vals,
                           unsigned* __restrict__ state, int pass) {
  __shared__ unsigned hist[16][257];   // 16 copies, padded stride to spread banks
  __shared__ unsigned hist1[256];
  const int tid = threadIdx.x;         // 1024 threads
  for (int i = tid; i < 16 * 257; i += 1024) (&hist[0][0])[i] = 0;
  __syncthreads();

  unsigned prefix = 0, krem = KSEL, pmask = 0;
  const int shift = 24 - 8 * pass;
  if (pass > 0) {
    prefix = state[0];
    krem   = state[1];
    pmask  = 0xFFFFFFFFu << (shift + 8);
  }
  const int copy = tid & 15;
  for (int i = tid; i < BTOT; i += 1024) {
    const unsigned u = vals[i];
    if ((u & pmask) == prefix)
      atomicAdd(&hist[copy][(u >> shift) & 255], 1u);
  }
  __syncthreads();
  if (tid < 256) {
    unsigned t = 0;
#pragma unroll
    for (int c = 0; c < 16; ++c) t += hist[c][tid];
    hist1[tid] = t;
  }
  __syncthreads();
  if (tid == 0) {
    unsigned k = krem, p = prefix;
    for (int bkt = 255; bkt >= 0; --bkt) {
      const unsigned c = hist1[bkt];
      if (k <= c) { p |= ((unsigned)bkt) << shift; break; }
      k -= c;
    }
    state[0] = p;   // after pass 3: exact bit pattern of the k-th largest loss
    state[1] = k;
  }
}

// ---------------- deterministic sum/count of values strictly greater than t ----------------
__global__ void ohem_sum(const float* __restrict__ losses,
                         const unsigned* __restrict__ state,
                         float* __restrict__ psum, unsigned* __restrict__ pcnt) {
  const unsigned ut = state[0];
  const int i = blockIdx.x * 256 + threadIdx.x;   // 256 blocks x 256 = 65536
  const float v = losses[i];
  const unsigned u = __float_as_uint(v);
  float    sv = (u > ut) ? v  : 0.f;
  unsigned sc = (u > ut) ? 1u : 0u;
#pragma unroll
  for (int st = 32; st >= 1; st >>= 1) {
    sv += __shfl_xor(sv, st, 64);
    sc += __shfl_xor(sc, st, 64);
  }
  __shared__ float    wsum[4];
  __shared__ unsigned wcnt[4];
  const int w = threadIdx.x >> 6;
  if ((threadIdx.x & 63) == 0) { wsum[w] = sv; wcnt[w] = sc; }
  __syncthreads();
  if (threadIdx.x == 0) {
    psum[blockIdx.x] = wsum[0] + wsum[1] + wsum[2] + wsum[3];
    pcnt[blockIdx.x] = wcnt[0] + wcnt[1] + wcnt[2] + wcnt[3];
  }
}

__global__ void ohem_final(const float* __restrict__ psum,
                           const unsigned* __restrict__ pcnt,
                           const unsigned* __restrict__ state,
                           float* __restrict__ out) {
  float    sv = psum[threadIdx.x];   // 256 threads
  unsigned sc = pcnt[threadIdx.x];
#pragma unroll
  for (int st = 32; st >= 1; st >>= 1) {
    sv += __shfl_xor(sv, st, 64);
    sc += __shfl_xor(sc, st, 64);
  }
  __shared__ float    wsum[4];
  __shared__ unsigned wcnt[4];
  const int w = threadIdx.x >> 6;
  if ((threadIdx.x & 63) == 0) { wsum[w] = sv; wcnt[w] = sc; }
  __syncthreads();
  if (threadIdx.x == 0) {
    const float    sum = wsum[0] + wsum[1] + wsum[2] + wsum[3];
    const unsigned cnt = wcnt[0] + wcnt[1] + wcnt[2] + wcnt[3];
    const float t = __uint_as_float(state[0]);
    out[0] = (sum + (float)(KSEL - cnt) * t) / (float)KSEL;
  }
}

extern "C" void kernel_launch(void* const* d_in, const int* in_sizes, int n_in,
                              void* d_out, int out_size, void* d_ws, size_t ws_size,
                              hipStream_t stream) {
  const float* feat    = (const float*)d_in[0];
  const int*   targets = (const int*)d_in[1];
  const float* W       = (const float*)d_in[2];
  const float* b       = (const float*)d_in[3];
  float* out = (float*)d_out;

  char* ws = (char*)d_ws;
  unsigned short* Wt     = (unsigned short*)ws;                         // 1 MiB
  float*          bp     = (float*)(ws + 1048576);                      // 4 KiB
  float*          losses = (float*)(ws + 1048576 + 4096);               // 256 KiB
  unsigned*       state  = (unsigned*)(ws + 1048576 + 4096 + 262144);   // 64 B
  float*          psum   = (float*)(ws + 1048576 + 4096 + 262144 + 256);
  unsigned*       pcnt   = (unsigned*)(ws + 1048576 + 4096 + 262144 + 256 + 1024);

  prep_wt<<<2048, 256, 0, stream>>>(W, Wt);
  prep_bias<<<4, 256, 0, stream>>>(b, bp);
  ohem_losses<<<512, 256, 0, stream>>>(feat, targets, Wt, bp, losses);
  radix_pass<<<1, 1024, 0, stream>>>((const unsigned*)losses, state, 0);
  radix_pass<<<1, 1024, 0, stream>>>((const unsigned*)losses, state, 1);
  radix_pass<<<1, 1024, 0, stream>>>((const unsigned*)losses, state, 2);
  radix_pass<<<1, 1024, 0, stream>>>((const unsigned*)losses, state, 3);
  ohem_sum<<<256, 256, 0, stream>>>(losses, state, psum, pcnt);
  ohem_final<<<1, 256, 0, stream>>>(psum, pcnt, state, out);
}

// Round 2
// 288.700 us; speedup vs baseline: 1.2000x; 1.2000x over previous
//
#include <hip/hip_runtime.h>
#include <hip/hip_bf16.h>

#define BTOT 65536
#define DDIM 512
#define CDIM 1000
#define KSEL 45875   // int(65536 * 0.7)

#define L2E 1.44269504088896340736f
#define LN2 0.69314718055994530942f
#define NEG_BIG -1.0e30f

typedef __attribute__((ext_vector_type(8))) short short8;
typedef __attribute__((ext_vector_type(8))) unsigned short ushort8;
typedef __attribute__((ext_vector_type(4))) float f32x4;

__device__ __forceinline__ unsigned short f2bf(float f) {
  unsigned u = __float_as_uint(f);
  u += 0x7FFFu + ((u >> 16) & 1u);
  return (unsigned short)(u >> 16);
}

__device__ __forceinline__ void gload_lds16(const void* g, void* l) {
  __builtin_amdgcn_global_load_lds(
      (const __attribute__((address_space(1))) unsigned int*)g,
      (__attribute__((address_space(3))) unsigned int*)l, 16, 0, 0);
}

// ---- prep: W [512][1000] f32 -> Wg: 32 chunks of [32 cols][512 k] bf16, XOR-swizzled image ----
// Within a chunk, element (cc,k) lives at byte ((cc<<10)|(k<<1)) ^ ((cc&7)<<4).
__global__ void prep_wt(const float* __restrict__ W, unsigned short* __restrict__ Wg) {
  const int idx = blockIdx.x * 256 + threadIdx.x;   // 65536 threads
  const int c  = idx & 1023;                        // padded col
  const int k8 = idx >> 10;                         // 0..63 (k = k8*8)
  const int nc = c >> 5, cc = c & 31;
  ushort8 v;
#pragma unroll
  for (int j = 0; j < 8; ++j) {
    const int k = k8 * 8 + j;
    v[j] = (c < CDIM) ? f2bf(W[k * CDIM + c]) : (unsigned short)0;
  }
  const unsigned dst = (unsigned)nc * 32768u +
      (((((unsigned)cc) << 10) | (((unsigned)k8) << 4)) ^ ((((unsigned)cc) & 7u) << 4));
  *(ushort8*)((char*)Wg + dst) = v;
}

__global__ void prep_bias(const float* __restrict__ b, float* __restrict__ bp) {
  const int i = blockIdx.x * 256 + threadIdx.x;     // < 1024
  bp[i] = (i < CDIM) ? b[i] * L2E : NEG_BIG;
}

__global__ void zero_hist(unsigned* __restrict__ h) {
  ((uint4*)h)[blockIdx.x * 256 + threadIdx.x] = (uint4){0, 0, 0, 0};  // 128*256*16B = 512 KB
}

// ---- fused GEMM + fixed-max logsumexp + target extraction + hi-16 histogram ----
// 512 blocks x 256 thr (4 waves). Wave owns 32 rows (A panel in regs); B double-buffered in LDS.
__launch_bounds__(256, 2)
__global__ void ohem_losses(const float* __restrict__ feat,
                            const int* __restrict__ targets,
                            const unsigned short* __restrict__ Wg,
                            const float* __restrict__ bpad,
                            float* __restrict__ losses,
                            unsigned* __restrict__ histHi) {
  __shared__ unsigned char lbuf[2][32768];
  const int tid  = threadIdx.x;
  const int lane = tid & 63;
  const int wave = (blockIdx.x << 2) + (tid >> 6);
  const int rowB = wave << 5;
  const int l15  = lane & 15;
  const int lgrp = lane >> 4;

  // prologue: stage chunk 0 into buf 0 (overlaps with panel load below)
#pragma unroll
  for (int r = 0; r < 8; ++r) {
    const int off = (r * 256 + tid) * 16;
    gload_lds16((const char*)Wg + off, &lbuf[0][off]);
  }

  // A panel: a[rf][ks] = rows rowB+rf*16+l15, k = ks*32 + lgrp*8 + j
  short8 a[2][16];
#pragma unroll
  for (int rf = 0; rf < 2; ++rf) {
    const float* src = feat + (size_t)(rowB + rf * 16 + l15) * DDIM + lgrp * 8;
#pragma unroll
    for (int ks = 0; ks < 16; ++ks) {
      const float4 f0 = *(const float4*)(src + ks * 32);
      const float4 f1 = *(const float4*)(src + ks * 32 + 4);
      short8 v;
      v[0] = (short)f2bf(f0.x); v[1] = (short)f2bf(f0.y);
      v[2] = (short)f2bf(f0.z); v[3] = (short)f2bf(f0.w);
      v[4] = (short)f2bf(f1.x); v[5] = (short)f2bf(f1.y);
      v[6] = (short)f2bf(f1.z); v[7] = (short)f2bf(f1.w);
      a[rf][ks] = v;
    }
  }

  int   tcol[8];
  float s[8], tv[8];
#pragma unroll
  for (int rf = 0; rf < 2; ++rf)
#pragma unroll
    for (int r = 0; r < 4; ++r) {
      const int slot = rf * 4 + r;
      tcol[slot] = targets[rowB + rf * 16 + lgrp * 4 + r];
      s[slot] = 0.f; tv[slot] = NEG_BIG;
    }

  __syncthreads();   // chunk 0 resident (syncthreads drains vmcnt)

  const unsigned xm    = ((unsigned)(l15 & 7)) << 4;
  const unsigned base0 = (((unsigned)l15) << 10) | (((unsigned)lgrp) << 4);
  const unsigned base1 = base0 + (16u << 10);

  for (int nc = 0; nc < 32; ++nc) {
    const int cur = nc & 1;
    if (nc + 1 < 32) {   // stage next chunk into the other buffer
      const char* src = (const char*)Wg + (size_t)(nc + 1) * 32768;
#pragma unroll
      for (int r = 0; r < 8; ++r) {
        const int off = (r * 256 + tid) * 16;
        gload_lds16(src + off, &lbuf[cur ^ 1][off]);
      }
    }

    f32x4 acc[2][2];
#pragma unroll
    for (int rf = 0; rf < 2; ++rf)
#pragma unroll
      for (int cf = 0; cf < 2; ++cf) acc[rf][cf] = (f32x4){0.f, 0.f, 0.f, 0.f};

    const unsigned char* lb = &lbuf[cur][0];
#pragma unroll
    for (int ks = 0; ks < 16; ++ks) {
      const unsigned o0 = (base0 | (((unsigned)ks) << 6)) ^ xm;
      const unsigned o1 = (base1 | (((unsigned)ks) << 6)) ^ xm;
      const short8 b0 = *(const short8*)(lb + o0);
      const short8 b1 = *(const short8*)(lb + o1);
      acc[0][0] = __builtin_amdgcn_mfma_f32_16x16x32_bf16(a[0][ks], b0, acc[0][0], 0, 0, 0);
      acc[0][1] = __builtin_amdgcn_mfma_f32_16x16x32_bf16(a[0][ks], b1, acc[0][1], 0, 0, 0);
      acc[1][0] = __builtin_amdgcn_mfma_f32_16x16x32_bf16(a[1][ks], b0, acc[1][0], 0, 0, 0);
      acc[1][1] = __builtin_amdgcn_mfma_f32_16x16x32_bf16(a[1][ks], b1, acc[1][1], 0, 0, 0);
    }

    const int col0 = (nc << 5) + l15;
    const int col1 = col0 + 16;
    const float bb0 = bpad[col0];   // pre-scaled by log2e; -1e30 masks padded cols
    const float bb1 = bpad[col1];
#pragma unroll
    for (int rf = 0; rf < 2; ++rf)
#pragma unroll
      for (int r = 0; r < 4; ++r) {
        const int slot = rf * 4 + r;
        const float z0 = fmaf(acc[rf][0][r], L2E, bb0);
        const float z1 = fmaf(acc[rf][1][r], L2E, bb1);
        if (col0 == tcol[slot]) tv[slot] = z0;
        if (col1 == tcol[slot]) tv[slot] = z1;
        s[slot] += __builtin_amdgcn_exp2f(z0) + __builtin_amdgcn_exp2f(z1);
      }

    __syncthreads();   // next chunk staged + all waves done reading cur
  }

  // merge across the 16-lane group (pure sums; tv held by exactly one lane)
#pragma unroll
  for (int st = 1; st <= 8; st <<= 1)
#pragma unroll
    for (int slot = 0; slot < 8; ++slot) {
      s[slot] += __shfl_xor(s[slot], st, 64);
      tv[slot] = fmaxf(tv[slot], __shfl_xor(tv[slot], st, 64));
    }

  if (l15 == 0) {
#pragma unroll
    for (int rf = 0; rf < 2; ++rf)
#pragma unroll
      for (int r = 0; r < 4; ++r) {
        const int slot = rf * 4 + r;
        float loss = LN2 * (__builtin_amdgcn_logf(s[slot]) - tv[slot]);
        loss = fmaxf(loss, 0.f);
        losses[rowB + rf * 16 + lgrp * 4 + r] = loss;
        atomicAdd(&histHi[__float_as_uint(loss) >> 16], 1u);
      }
  }
}

// ---- level scan: find bin containing the k-th largest; 1 block x 256 threads ----
__global__ void scan_level(const unsigned* __restrict__ hist,
                           unsigned* __restrict__ state, const int level) {
  const int t = threadIdx.x;
  __shared__ unsigned sh[256];
  const unsigned k       = (level == 0) ? (unsigned)KSEL : state[1];
  const unsigned oldpref = (level == 0) ? 0u : state[0];

  unsigned gs = 0;
  const uint4* hp = (const uint4*)(hist + t * 256);
#pragma unroll 4
  for (int i = 0; i < 64; ++i) { const uint4 h = hp[i]; gs += h.x + h.y + h.z + h.w; }
  sh[t] = gs;
  __syncthreads();
  for (int off = 1; off < 256; off <<= 1) {   // inclusive suffix scan
    unsigned v = sh[t];
    if (t + off < 256) v += sh[t + off];
    __syncthreads();
    sh[t] = v;
    __syncthreads();
  }
  const unsigned incl  = sh[t];
  const unsigned above = (t < 255) ? sh[t + 1] : 0u;
  if (above < k && k <= incl) {          // exactly one thread
    unsigned kk = k - above;
    int b = 255;
    for (; b > 0; --b) {
      const unsigned c = hist[t * 256 + b];
      if (kk <= c) break;
      kk -= c;
    }
    const unsigned bin = (unsigned)(t * 256 + b);
    if (level == 0) { state[0] = bin << 16;      state[1] = kk; }
    else            { state[0] = oldpref | bin;  state[1] = kk; }
  }
}

__global__ void hist_lo(const float* __restrict__ losses,
                        const unsigned* __restrict__ state,
                        unsigned* __restrict__ hLo) {
  const unsigned pref = state[0] >> 16;
  const int i = blockIdx.x * 256 + threadIdx.x;
  const unsigned u = ((const unsigned*)losses)[i];
  if ((u >> 16) == pref) atomicAdd(&hLo[u & 0xFFFFu], 1u);
}

// ---- deterministic sum/count of values strictly greater than threshold ----
__global__ void ohem_sum(const float* __restrict__ losses,
                         const unsigned* __restrict__ state,
                         float* __restrict__ psum, unsigned* __restrict__ pcnt) {
  const unsigned ut = state[0];
  const int i = blockIdx.x * 256 + threadIdx.x;
  const float v = losses[i];
  const unsigned u = __float_as_uint(v);
  float    sv = (u > ut) ? v  : 0.f;
  unsigned sc = (u > ut) ? 1u : 0u;
#pragma unroll
  for (int st = 32; st >= 1; st >>= 1) {
    sv += __shfl_xor(sv, st, 64);
    sc += __shfl_xor(sc, st, 64);
  }
  __shared__ float    wsum[4];
  __shared__ unsigned wcnt[4];
  const int w = threadIdx.x >> 6;
  if ((threadIdx.x & 63) == 0) { wsum[w] = sv; wcnt[w] = sc; }
  __syncthreads();
  if (threadIdx.x == 0) {
    psum[blockIdx.x] = wsum[0] + wsum[1] + wsum[2] + wsum[3];
    pcnt[blockIdx.x] = wcnt[0] + wcnt[1] + wcnt[2] + wcnt[3];
  }
}

__global__ void ohem_final(const float* __restrict__ psum,
                           const unsigned* __restrict__ pcnt,
                           const unsigned* __restrict__ state,
                           float* __restrict__ out) {
  float    sv = psum[threadIdx.x];
  unsigned sc = pcnt[threadIdx.x];
#pragma unroll
  for (int st = 32; st >= 1; st >>= 1) {
    sv += __shfl_xor(sv, st, 64);
    sc += __shfl_xor(sc, st, 64);
  }
  __shared__ float    wsum[4];
  __shared__ unsigned wcnt[4];
  const int w = threadIdx.x >> 6;
  if ((threadIdx.x & 63) == 0) { wsum[w] = sv; wcnt[w] = sc; }
  __syncthreads();
  if (threadIdx.x == 0) {
    const float    sum = wsum[0] + wsum[1] + wsum[2] + wsum[3];
    const unsigned cnt = wcnt[0] + wcnt[1] + wcnt[2] + wcnt[3];
    const float t = __uint_as_float(state[0]);
    out[0] = (sum + (float)(KSEL - cnt) * t) / (float)KSEL;
  }
}

extern "C" void kernel_launch(void* const* d_in, const int* in_sizes, int n_in,
                              void* d_out, int out_size, void* d_ws, size_t ws_size,
                              hipStream_t stream) {
  const float* feat    = (const float*)d_in[0];
  const int*   targets = (const int*)d_in[1];
  const float* W       = (const float*)d_in[2];
  const float* b       = (const float*)d_in[3];
  float* out = (float*)d_out;

  char* ws = (char*)d_ws;
  unsigned short* Wg     = (unsigned short*)ws;                 // 1 MiB (swizzled image)
  float*          bp     = (float*)(ws + 1048576);              // 4 KiB
  float*          losses = (float*)(ws + 1052672);              // 256 KiB
  unsigned*       hHi    = (unsigned*)(ws + 1314816);           // 256 KiB
  unsigned*       hLo    = (unsigned*)(ws + 1576960);           // 256 KiB
  unsigned*       state  = (unsigned*)(ws + 1839104);           // 256 B
  float*          psum   = (float*)(ws + 1839360);              // 1 KiB
  unsigned*       pcnt   = (unsigned*)(ws + 1840384);           // 1 KiB

  zero_hist<<<128, 256, 0, stream>>>(hHi);                      // zeroes hHi+hLo (contiguous 512 KiB)
  prep_wt<<<256, 256, 0, stream>>>(W, Wg);
  prep_bias<<<4, 256, 0, stream>>>(b, bp);
  ohem_losses<<<512, 256, 0, stream>>>(feat, targets, Wg, bp, losses, hHi);
  scan_level<<<1, 256, 0, stream>>>(hHi, state, 0);
  hist_lo<<<256, 256, 0, stream>>>(losses, state, hLo);
  scan_level<<<1, 256, 0, stream>>>(hLo, state, 1);
  ohem_sum<<<256, 256, 0, stream>>>(losses, state, psum, pcnt);
  ohem_final<<<1, 256, 0, stream>>>(psum, pcnt, state, out);
}